// Round 5
// baseline (2088.902 us; speedup 1.0000x reference)
//
#include <hip/hip_runtime.h>
#include <math.h>

#define H 16
#define HD 64
#define DDIM 1024
#define LSEQ 1024
#define BATCH 4
#define TOPK 102
#define INV_SCALE 0.125f
#define MROWS (LSEQ * BATCH)   // 4096
#define QKVN (3 * DDIM)        // 3072
#define HBL (H * BATCH * LSEQ) // 65536

// ---------------- fp32 tiled GEMM: C = A(M,K) * B(N,K)^T + bias(N) ----------------
// 128x128 tile, 8x8 split microtile. PERMUTE=true scatters output into
// Q/K/V buffers laid out (H,B,L,64) for the fused attention kernel.
#define BM 128
#define BN 128
#define BKK 16

template <bool PERMUTE>
__global__ __launch_bounds__(256)
void gemm_abT_bias(const float* __restrict__ A, const float* __restrict__ Bw,
                   const float* __restrict__ bias, float* __restrict__ C,
                   int Nd, int Kd) {
    __shared__ float As[BKK][BM + 4];
    __shared__ float Bs[BKK][BN + 4];
    const int tid = threadIdx.x;
    const int tx = tid & 15, ty = tid >> 4;
    const int bn = blockIdx.x * BN, bm = blockIdx.y * BM;
    const int lr = tid >> 1;          // 0..127
    const int lc = (tid & 1) * 8;     // 0 or 8
    const float* Aptr = A + (size_t)(bm + lr) * Kd + lc;
    const float* Bptr = Bw + (size_t)(bn + lr) * Kd + lc;

    float acc[2][2][4][4];
    #pragma unroll
    for (int r = 0; r < 2; ++r)
        #pragma unroll
        for (int c = 0; c < 2; ++c)
            #pragma unroll
            for (int i = 0; i < 4; ++i)
                #pragma unroll
                for (int j = 0; j < 4; ++j) acc[r][c][i][j] = 0.0f;

    float4 av0 = *(const float4*)(Aptr);
    float4 av1 = *(const float4*)(Aptr + 4);
    float4 bv0 = *(const float4*)(Bptr);
    float4 bv1 = *(const float4*)(Bptr + 4);

    for (int k0 = 0; k0 < Kd; k0 += BKK) {
        __syncthreads();
        As[lc + 0][lr] = av0.x; As[lc + 1][lr] = av0.y; As[lc + 2][lr] = av0.z; As[lc + 3][lr] = av0.w;
        As[lc + 4][lr] = av1.x; As[lc + 5][lr] = av1.y; As[lc + 6][lr] = av1.z; As[lc + 7][lr] = av1.w;
        Bs[lc + 0][lr] = bv0.x; Bs[lc + 1][lr] = bv0.y; Bs[lc + 2][lr] = bv0.z; Bs[lc + 3][lr] = bv0.w;
        Bs[lc + 4][lr] = bv1.x; Bs[lc + 5][lr] = bv1.y; Bs[lc + 6][lr] = bv1.z; Bs[lc + 7][lr] = bv1.w;
        __syncthreads();
        if (k0 + BKK < Kd) {
            av0 = *(const float4*)(Aptr + k0 + BKK);
            av1 = *(const float4*)(Aptr + k0 + BKK + 4);
            bv0 = *(const float4*)(Bptr + k0 + BKK);
            bv1 = *(const float4*)(Bptr + k0 + BKK + 4);
        }
        #pragma unroll
        for (int kk = 0; kk < BKK; ++kk) {
            float ar[8], br[8];
            *(float4*)&ar[0] = *(const float4*)&As[kk][ty * 4];
            *(float4*)&ar[4] = *(const float4*)&As[kk][64 + ty * 4];
            *(float4*)&br[0] = *(const float4*)&Bs[kk][tx * 4];
            *(float4*)&br[4] = *(const float4*)&Bs[kk][64 + tx * 4];
            #pragma unroll
            for (int r = 0; r < 2; ++r)
                #pragma unroll
                for (int i = 0; i < 4; ++i)
                    #pragma unroll
                    for (int c = 0; c < 2; ++c)
                        #pragma unroll
                        for (int j = 0; j < 4; ++j)
                            acc[r][c][i][j] += ar[r * 4 + i] * br[c * 4 + j];
        }
    }
    float4 bb[2];
    bb[0] = *(const float4*)&bias[bn + tx * 4];
    bb[1] = *(const float4*)&bias[bn + 64 + tx * 4];
    #pragma unroll
    for (int r = 0; r < 2; ++r)
        #pragma unroll
        for (int i = 0; i < 4; ++i) {
            const int row = bm + r * 64 + ty * 4 + i;
            #pragma unroll
            for (int c = 0; c < 2; ++c) {
                float4 o;
                o.x = acc[r][c][i][0] + bb[c].x;
                o.y = acc[r][c][i][1] + bb[c].y;
                o.z = acc[r][c][i][2] + bb[c].z;
                o.w = acc[r][c][i][3] + bb[c].w;
                if (!PERMUTE) {
                    *(float4*)&C[(size_t)row * Nd + bn + c * 64 + tx * 4] = o;
                } else {
                    const int col = bn + c * 64 + tx * 4;
                    const int which = col >> 10;          // 0=q,1=k,2=v
                    const int hh = (col >> 6) & 15;
                    const int d = col & 63;               // = tx*4
                    const int l = row >> 2, b2 = row & 3; // row = l*B + b
                    float* dst = C + (size_t)which * ((size_t)HBL * HD)
                               + (((size_t)(hh * BATCH + b2) * LSEQ + l) * HD + d);
                    *(float4*)dst = o;
                }
            }
        }
}

// ---------------- fused scores + topk + softmax + sparse PV ----------------
// One block = 256 threads = 4 waves = 4 rows of one (h,b) slice.
// Scores stored in LDS as order-preserving u32 keys. Top-k via per-wave
// byte-histogram radix select (<=4 passes, usually early-exits after 2).
__global__ __launch_bounds__(256, 4)
void fused_attn(const float* __restrict__ Q, const float* __restrict__ K,
                const float* __restrict__ V, const float* __restrict__ S,
                float* __restrict__ attn) {
    __shared__ unsigned sc[4][LSEQ];     // 16 KB  (u32 keys)
    __shared__ int      hist[4][256];    // 4 KB   (per-wave histogram)
    __shared__ float    qs[4][HD];       // 1 KB
    __shared__ int      idxs[4][TOPK];   // 1.6 KB
    __shared__ float    wts[4][TOPK];    // 1.6 KB

    const int h = blockIdx.z, b = blockIdx.y, l0 = blockIdx.x * 4;
    const int tid = threadIdx.x;
    const size_t hb = (size_t)(h * BATCH + b) * LSEQ;

    // Phase A: stage 4 q rows
    if (tid < 64) {
        const int r = tid >> 4, d4 = (tid & 15) * 4;
        *(float4*)&qs[r][d4] = *(const float4*)&Q[(hb + l0 + r) * HD + d4];
    }
    __syncthreads();

    // Phase B: scores for t = tid*4..+3 against 4 rows; store transformed keys
    {
        const int t0 = tid * 4;
        float acc[4][4];
        #pragma unroll
        for (int r = 0; r < 4; ++r)
            #pragma unroll
            for (int c = 0; c < 4; ++c) acc[r][c] = 0.0f;

        const float* kp = K + (hb + t0) * HD;
        #pragma unroll
        for (int dc = 0; dc < 16; ++dc) {
            float4 k0 = *(const float4*)(kp + 0 * HD + dc * 4);
            float4 k1 = *(const float4*)(kp + 1 * HD + dc * 4);
            float4 k2 = *(const float4*)(kp + 2 * HD + dc * 4);
            float4 k3 = *(const float4*)(kp + 3 * HD + dc * 4);
            #pragma unroll
            for (int r = 0; r < 4; ++r) {
                float4 q4 = *(const float4*)&qs[r][dc * 4];
                acc[r][0] += q4.x * k0.x + q4.y * k0.y + q4.z * k0.z + q4.w * k0.w;
                acc[r][1] += q4.x * k1.x + q4.y * k1.y + q4.z * k1.z + q4.w * k1.w;
                acc[r][2] += q4.x * k2.x + q4.y * k2.y + q4.z * k2.z + q4.w * k2.w;
                acc[r][3] += q4.x * k3.x + q4.y * k3.y + q4.z * k3.z + q4.w * k3.w;
            }
        }
        #pragma unroll
        for (int r = 0; r < 4; ++r) {
            float4 s4 = *(const float4*)&S[((size_t)h * DDIM + (l0 + r)) * DDIM + t0];
            float v0 = acc[r][0] * INV_SCALE + __logf(s4.x + 1e-8f);
            float v1 = acc[r][1] * INV_SCALE + __logf(s4.y + 1e-8f);
            float v2 = acc[r][2] * INV_SCALE + __logf(s4.z + 1e-8f);
            float v3 = acc[r][3] * INV_SCALE + __logf(s4.w + 1e-8f);
            uint4 o;
            unsigned b0 = __float_as_uint(v0), b1 = __float_as_uint(v1);
            unsigned b2 = __float_as_uint(v2), b3 = __float_as_uint(v3);
            o.x = ((int)b0 < 0) ? ~b0 : (b0 | 0x80000000u);
            o.y = ((int)b1 < 0) ? ~b1 : (b1 | 0x80000000u);
            o.z = ((int)b2 < 0) ? ~b2 : (b2 | 0x80000000u);
            o.w = ((int)b3 < 0) ? ~b3 : (b3 | 0x80000000u);
            *(uint4*)&sc[r][t0] = o;
        }
    }
    __syncthreads();

    // Phase C: per-wave histogram radix select + softmax + compaction (row = wave)
    const int w = tid >> 6, lane = tid & 63;
    const unsigned long long lt = (1ull << lane) - 1ull;

    unsigned u[16];
    unsigned mxu = 0;
    #pragma unroll
    for (int i = 0; i < 16; ++i) {
        u[i] = sc[w][i * 64 + lane];
        mxu = (u[i] > mxu) ? u[i] : mxu;
    }
    #pragma unroll
    for (int off = 32; off; off >>= 1) {
        unsigned o2 = (unsigned)__shfl_xor((int)mxu, off);
        mxu = (o2 > mxu) ? o2 : mxu;
    }
    const unsigned mbits = (mxu & 0x80000000u) ? (mxu & 0x7fffffffu) : ~mxu;
    const float mxf = __uint_as_float(mbits);

    unsigned prefix = 0, thr = 0;
    int need = TOPK;
    bool early = false;
    for (int pass = 0; pass < 4; ++pass) {
        const int shift = 24 - 8 * pass;
        hist[w][lane] = 0; hist[w][lane + 64] = 0;
        hist[w][lane + 128] = 0; hist[w][lane + 192] = 0;
        #pragma unroll
        for (int i = 0; i < 16; ++i) {
            const bool act = (pass == 0) || ((u[i] >> (shift + 8)) == prefix);
            if (act) atomicAdd(&hist[w][(u[i] >> shift) & 255], 1);
        }
        const int4 bb = *(const int4*)&hist[w][lane * 4];
        int Ssum = bb.x + bb.y + bb.z + bb.w;
        #pragma unroll
        for (int off = 1; off < 64; off <<= 1) {
            const int t = __shfl_down(Ssum, off);
            if (lane + off < 64) Ssum += t;
        }
        const unsigned long long bal = __ballot(Ssum >= need);
        const int lstar = (int)__popcll(bal) - 1;
        const int above = (lstar < 63) ? __shfl(Ssum, lstar + 1) : 0;
        const int c0 = __shfl(bb.x, lstar), c1 = __shfl(bb.y, lstar);
        const int c2 = __shfl(bb.z, lstar), c3 = __shfl(bb.w, lstar);
        const int s3 = above + c3, s2 = s3 + c2, s1 = s2 + c1;
        int dstar, cbkt, selab;
        if (s3 >= need)      { dstar = 3; cbkt = c3; selab = above; }
        else if (s2 >= need) { dstar = 2; cbkt = c2; selab = s3; }
        else if (s1 >= need) { dstar = 1; cbkt = c1; selab = s2; }
        else                 { dstar = 0; cbkt = c0; selab = s1; }
        prefix = (prefix << 8) | (unsigned)(lstar * 4 + dstar);
        need -= selab;
        if (cbkt == need) { early = true; thr = prefix << shift; break; }
    }
    if (!early) thr = prefix;   // exact k-th key; `need` ties kept (ascending t)

    float p[16]; float lsum = 0.0f; unsigned selmask = 0;
    int cum = 0;
    #pragma unroll
    for (int i = 0; i < 16; ++i) {
        bool sel;
        if (early) {
            sel = (u[i] >= thr);
        } else {
            const bool eq = (u[i] == thr);
            const unsigned long long em = __ballot(eq);
            const int erank = cum + (int)__popcll(em & lt);
            cum += (int)__popcll(em);
            sel = (u[i] > thr) || (eq && erank < need);
        }
        const unsigned ub = u[i];
        const unsigned bits = (ub & 0x80000000u) ? (ub & 0x7fffffffu) : ~ub;
        const float s = __uint_as_float(bits);
        p[i] = sel ? __expf(s - mxf) : 0.0f;
        if (sel) selmask |= (1u << i);
        lsum += p[i];
    }
    #pragma unroll
    for (int off = 32; off; off >>= 1) lsum += __shfl_xor(lsum, off);
    const float inv = 1.0f / lsum;

    int pos = 0;
    #pragma unroll
    for (int i = 0; i < 16; ++i) {
        const bool sel = (selmask >> i) & 1u;
        const unsigned long long sm = __ballot(sel);
        const int mypos = pos + (int)__popcll(sm & lt);
        if (sel) { idxs[w][mypos] = i * 64 + lane; wts[w][mypos] = p[i] * inv; }
        pos += (int)__popcll(sm);
    }

    // Phase D: sparse PV (lane = d), V rows are 256B coalesced L2 hits
    const float* vb = V + hb * HD + lane;
    float o0 = 0.0f, o1 = 0.0f;
    for (int j = 0; j < TOPK; j += 2) {
        const int2 ii = *(const int2*)&idxs[w][j];
        const float2 ww = *(const float2*)&wts[w][j];
        o0 += ww.x * vb[(size_t)ii.x * HD];
        o1 += ww.y * vb[(size_t)ii.y * HD];
    }
    attn[((size_t)(l0 + w) * BATCH + b) * DDIM + h * HD + lane] = o0 + o1;
}

// ---------------- launcher ----------------
extern "C" void kernel_launch(void* const* d_in, const int* in_sizes, int n_in,
                              void* d_out, int out_size, void* d_ws, size_t ws_size,
                              hipStream_t stream) {
    (void)in_sizes; (void)n_in; (void)out_size; (void)ws_size;
    const float* x      = (const float*)d_in[0];
    const float* qkv_w  = (const float*)d_in[1];
    const float* qkv_b  = (const float*)d_in[2];
    const float* out_w  = (const float*)d_in[3];
    const float* out_b  = (const float*)d_in[4];
    const float* S      = (const float*)d_in[5];
    float* out = (float*)d_out;

    // workspace: Q|K|V (each HBL x 64) + attn (L*B x D)  = 67 MB total
    float* Q    = (float*)d_ws;
    float* Kb   = Q + (size_t)HBL * HD;
    float* V    = Kb + (size_t)HBL * HD;
    float* attn = V + (size_t)HBL * HD;

    // K1: qkv = x @ qkv_w^T + qkv_b, scattered into Q/K/V (H,B,L,64)
    gemm_abT_bias<true><<<dim3(QKVN / BN, MROWS / BM), 256, 0, stream>>>(
        x, qkv_w, qkv_b, Q, QKVN, DDIM);

    // K2: fused scores + topk + softmax + sparse PV
    fused_attn<<<dim3(LSEQ / 4, BATCH, H), 256, 0, stream>>>(Q, Kb, V, S, attn);

    // K3: out = attn @ out_w^T + out_b
    gemm_abT_bias<false><<<dim3(DDIM / BN, MROWS / BM), 256, 0, stream>>>(
        attn, out_w, out_b, out, DDIM, DDIM);
}

// Round 6
// 1993.628 us; speedup vs baseline: 1.0478x; 1.0478x over previous
//
#include <hip/hip_runtime.h>
#include <math.h>

#define H 16
#define HD 64
#define DDIM 1024
#define LSEQ 1024
#define BATCH 4
#define TOPK 102
#define INV_SCALE 0.125f
#define MROWS (LSEQ * BATCH)   // 4096
#define QKVN (3 * DDIM)        // 3072
#define HBL (H * BATCH * LSEQ) // 65536

// ---------------- fp32 tiled GEMM: C = A(M,K) * B(N,K)^T + bias(N) ----------------
#define BM 128
#define BN 128
#define BKK 16

template <bool PERMUTE>
__global__ __launch_bounds__(256)
void gemm_abT_bias(const float* __restrict__ A, const float* __restrict__ Bw,
                   const float* __restrict__ bias, float* __restrict__ C,
                   int Nd, int Kd) {
    __shared__ float As[BKK][BM + 4];
    __shared__ float Bs[BKK][BN + 4];
    const int tid = threadIdx.x;
    const int tx = tid & 15, ty = tid >> 4;
    const int bn = blockIdx.x * BN, bm = blockIdx.y * BM;
    const int lr = tid >> 1;          // 0..127
    const int lc = (tid & 1) * 8;     // 0 or 8
    const float* Aptr = A + (size_t)(bm + lr) * Kd + lc;
    const float* Bptr = Bw + (size_t)(bn + lr) * Kd + lc;

    float acc[2][2][4][4];
    #pragma unroll
    for (int r = 0; r < 2; ++r)
        #pragma unroll
        for (int c = 0; c < 2; ++c)
            #pragma unroll
            for (int i = 0; i < 4; ++i)
                #pragma unroll
                for (int j = 0; j < 4; ++j) acc[r][c][i][j] = 0.0f;

    float4 av0 = *(const float4*)(Aptr);
    float4 av1 = *(const float4*)(Aptr + 4);
    float4 bv0 = *(const float4*)(Bptr);
    float4 bv1 = *(const float4*)(Bptr + 4);

    for (int k0 = 0; k0 < Kd; k0 += BKK) {
        __syncthreads();
        As[lc + 0][lr] = av0.x; As[lc + 1][lr] = av0.y; As[lc + 2][lr] = av0.z; As[lc + 3][lr] = av0.w;
        As[lc + 4][lr] = av1.x; As[lc + 5][lr] = av1.y; As[lc + 6][lr] = av1.z; As[lc + 7][lr] = av1.w;
        Bs[lc + 0][lr] = bv0.x; Bs[lc + 1][lr] = bv0.y; Bs[lc + 2][lr] = bv0.z; Bs[lc + 3][lr] = bv0.w;
        Bs[lc + 4][lr] = bv1.x; Bs[lc + 5][lr] = bv1.y; Bs[lc + 6][lr] = bv1.z; Bs[lc + 7][lr] = bv1.w;
        __syncthreads();
        if (k0 + BKK < Kd) {
            av0 = *(const float4*)(Aptr + k0 + BKK);
            av1 = *(const float4*)(Aptr + k0 + BKK + 4);
            bv0 = *(const float4*)(Bptr + k0 + BKK);
            bv1 = *(const float4*)(Bptr + k0 + BKK + 4);
        }
        #pragma unroll
        for (int kk = 0; kk < BKK; ++kk) {
            float ar[8], br[8];
            *(float4*)&ar[0] = *(const float4*)&As[kk][ty * 4];
            *(float4*)&ar[4] = *(const float4*)&As[kk][64 + ty * 4];
            *(float4*)&br[0] = *(const float4*)&Bs[kk][tx * 4];
            *(float4*)&br[4] = *(const float4*)&Bs[kk][64 + tx * 4];
            #pragma unroll
            for (int r = 0; r < 2; ++r)
                #pragma unroll
                for (int i = 0; i < 4; ++i)
                    #pragma unroll
                    for (int c = 0; c < 2; ++c)
                        #pragma unroll
                        for (int j = 0; j < 4; ++j)
                            acc[r][c][i][j] += ar[r * 4 + i] * br[c * 4 + j];
        }
    }
    float4 bb[2];
    bb[0] = *(const float4*)&bias[bn + tx * 4];
    bb[1] = *(const float4*)&bias[bn + 64 + tx * 4];
    #pragma unroll
    for (int r = 0; r < 2; ++r)
        #pragma unroll
        for (int i = 0; i < 4; ++i) {
            const int row = bm + r * 64 + ty * 4 + i;
            #pragma unroll
            for (int c = 0; c < 2; ++c) {
                float4 o;
                o.x = acc[r][c][i][0] + bb[c].x;
                o.y = acc[r][c][i][1] + bb[c].y;
                o.z = acc[r][c][i][2] + bb[c].z;
                o.w = acc[r][c][i][3] + bb[c].w;
                if (!PERMUTE) {
                    *(float4*)&C[(size_t)row * Nd + bn + c * 64 + tx * 4] = o;
                } else {
                    const int col = bn + c * 64 + tx * 4;
                    const int which = col >> 10;          // 0=q,1=k,2=v
                    const int hh = (col >> 6) & 15;
                    const int d = col & 63;               // = tx*4
                    const int l = row >> 2, b2 = row & 3; // row = l*B + b
                    float* dst = C + (size_t)which * ((size_t)HBL * HD)
                               + (((size_t)(hh * BATCH + b2) * LSEQ + l) * HD + d);
                    *(float4*)dst = o;
                }
            }
        }
}

// ---------------- fused scores + topk + softmax + sparse PV ----------------
// One block = 4 waves = 4 rows of one (h,b). Score keys live in LDS only
// (no register arrays -> no spills). Per-wave byte-histogram radix select,
// usually early-exits after 1-2 passes.
__global__ __launch_bounds__(256)
void fused_attn(const float* __restrict__ Q, const float* __restrict__ K,
                const float* __restrict__ V, const float* __restrict__ S,
                float* __restrict__ attn) {
    __shared__ unsigned sc[4][LSEQ];     // 16 KB  (u32 order-preserving keys)
    __shared__ int      hist[4][256];    // 4 KB   (bucket-swizzled)
    __shared__ float    qs[4][HD];       // 1 KB
    __shared__ int      idxs[4][TOPK];   // 1.6 KB
    __shared__ float    wts[4][TOPK];    // 1.6 KB

    const int h = blockIdx.z, b = blockIdx.y, l0 = blockIdx.x * 4;
    const int tid = threadIdx.x;
    const size_t hb = (size_t)(h * BATCH + b) * LSEQ;

    // Phase A: stage 4 q rows
    if (tid < 64) {
        const int r = tid >> 4, d4 = (tid & 15) * 4;
        *(float4*)&qs[r][d4] = *(const float4*)&Q[(hb + l0 + r) * HD + d4];
    }
    __syncthreads();

    // Phase B: thread handles cols t = tid + j*256 (stride-4B LDS stores,
    // conflict-free; K loads coalesced across lanes).
    #pragma unroll
    for (int j = 0; j < 4; ++j) {
        const int t = tid + j * 256;
        const float* kp = K + (hb + t) * HD;
        float ar[4] = {0.0f, 0.0f, 0.0f, 0.0f};
        #pragma unroll
        for (int dc = 0; dc < 16; ++dc) {
            const float4 kv = *(const float4*)(kp + dc * 4);
            #pragma unroll
            for (int r = 0; r < 4; ++r) {
                const float4 q4 = *(const float4*)&qs[r][dc * 4];
                ar[r] += q4.x * kv.x + q4.y * kv.y + q4.z * kv.z + q4.w * kv.w;
            }
        }
        const float* Scol = S + (size_t)h * DDIM * DDIM + t;
        #pragma unroll
        for (int r = 0; r < 4; ++r) {
            const float v = ar[r] * INV_SCALE + __logf(Scol[(size_t)(l0 + r) * DDIM] + 1e-8f);
            const unsigned bits = __float_as_uint(v);
            sc[r][t] = ((int)bits < 0) ? ~bits : (bits | 0x80000000u);
        }
    }
    __syncthreads();

    // Phase C: per-wave radix select (keys re-read from LDS each pass)
    const int w = tid >> 6, lane = tid & 63;
    const unsigned long long lt = (1ull << lane) - 1ull;
    const unsigned* skey = sc[w];

    unsigned mxu = 0;
    #pragma unroll
    for (int i = 0; i < 16; ++i) {
        const unsigned k = skey[i * 64 + lane];
        mxu = (k > mxu) ? k : mxu;
    }
    #pragma unroll
    for (int off = 32; off; off >>= 1) {
        const unsigned o2 = (unsigned)__shfl_xor((int)mxu, off);
        mxu = (o2 > mxu) ? o2 : mxu;
    }
    const unsigned mbits = (mxu & 0x80000000u) ? (mxu & 0x7fffffffu) : ~mxu;
    const float mxf = __uint_as_float(mbits);

    unsigned prefix = 0, thr = 0;
    int need = TOPK;
    bool early = false;
    for (int pass = 0; pass < 4; ++pass) {
        const int shift = 24 - 8 * pass;
        hist[w][lane] = 0; hist[w][lane + 64] = 0;
        hist[w][lane + 128] = 0; hist[w][lane + 192] = 0;
        #pragma unroll
        for (int i = 0; i < 16; ++i) {
            const unsigned k = skey[i * 64 + lane];
            if (pass == 0 || (k >> (shift + 8)) == prefix) {
                const unsigned bkt = (k >> shift) & 255u;
                atomicAdd(&hist[w][(bkt & 3u) * 64 + (bkt >> 2)], 1);   // swizzled
            }
        }
        // lane owns buckets 4*lane .. 4*lane+3 (each a conflict-free b32 read)
        const int c0 = hist[w][lane];
        const int c1 = hist[w][64 + lane];
        const int c2 = hist[w][128 + lane];
        const int c3 = hist[w][192 + lane];
        int Ssum = c0 + c1 + c2 + c3;
        #pragma unroll
        for (int off = 1; off < 64; off <<= 1) {
            const int t2 = __shfl_down(Ssum, off);
            if (lane + off < 64) Ssum += t2;
        }
        const unsigned long long bal = __ballot(Ssum >= need);
        const int lstar = (int)__popcll(bal) - 1;
        const int above = (lstar < 63) ? __shfl(Ssum, lstar + 1) : 0;
        const int b0 = __shfl(c0, lstar), b1 = __shfl(c1, lstar);
        const int b2 = __shfl(c2, lstar), b3 = __shfl(c3, lstar);
        const int s3 = above + b3, s2 = s3 + b2, s1 = s2 + b1;
        int dstar, cbkt, selab;
        if (s3 >= need)      { dstar = 3; cbkt = b3; selab = above; }
        else if (s2 >= need) { dstar = 2; cbkt = b2; selab = s3; }
        else if (s1 >= need) { dstar = 1; cbkt = b1; selab = s2; }
        else                 { dstar = 0; cbkt = b0; selab = s1; }
        prefix = (prefix << 8) | (unsigned)(lstar * 4 + dstar);
        need -= selab;
        if (cbkt == need) { early = true; thr = prefix << shift; break; }
    }
    if (!early) thr = prefix;   // exact k-th key; `need` ties kept (ascending t)

    // selection + softmax + compaction in one LDS pass (weights unnormalized)
    float lsum = 0.0f;
    int pos = 0, cum = 0;
    #pragma unroll
    for (int i = 0; i < 16; ++i) {
        const unsigned k = skey[i * 64 + lane];
        bool sel;
        if (early) {
            sel = (k >= thr);
        } else {
            const bool eq = (k == thr);
            const unsigned long long em = __ballot(eq);
            const int erank = cum + (int)__popcll(em & lt);
            cum += (int)__popcll(em);
            sel = (k > thr) || (eq && erank < need);
        }
        const unsigned long long sm = __ballot(sel);
        float pe = 0.0f;
        if (sel) {
            const unsigned bits = (k & 0x80000000u) ? (k & 0x7fffffffu) : ~k;
            pe = __expf(__uint_as_float(bits) - mxf);
            const int mypos = pos + (int)__popcll(sm & lt);
            idxs[w][mypos] = i * 64 + lane;
            wts[w][mypos] = pe;
        }
        pos += (int)__popcll(sm);
        lsum += pe;
    }
    #pragma unroll
    for (int off = 32; off; off >>= 1) lsum += __shfl_xor(lsum, off);
    const float inv = 1.0f / lsum;

    // Phase D: sparse PV (lane = d); normalize at the end
    const float* vb = V + hb * HD + lane;
    float o0 = 0.0f, o1 = 0.0f;
    for (int j = 0; j < TOPK; j += 2) {
        const int2 ii = *(const int2*)&idxs[w][j];
        const float2 ww = *(const float2*)&wts[w][j];
        o0 += ww.x * vb[(size_t)ii.x * HD];
        o1 += ww.y * vb[(size_t)ii.y * HD];
    }
    attn[((size_t)(l0 + w) * BATCH + b) * DDIM + h * HD + lane] = (o0 + o1) * inv;
}

// ---------------- launcher ----------------
extern "C" void kernel_launch(void* const* d_in, const int* in_sizes, int n_in,
                              void* d_out, int out_size, void* d_ws, size_t ws_size,
                              hipStream_t stream) {
    (void)in_sizes; (void)n_in; (void)out_size; (void)ws_size;
    const float* x      = (const float*)d_in[0];
    const float* qkv_w  = (const float*)d_in[1];
    const float* qkv_b  = (const float*)d_in[2];
    const float* out_w  = (const float*)d_in[3];
    const float* out_b  = (const float*)d_in[4];
    const float* S      = (const float*)d_in[5];
    float* out = (float*)d_out;

    // workspace: Q|K|V (each HBL x 64) + attn (L*B x D)  = 67 MB total
    float* Q    = (float*)d_ws;
    float* Kb   = Q + (size_t)HBL * HD;
    float* V    = Kb + (size_t)HBL * HD;
    float* attn = V + (size_t)HBL * HD;

    // K1: qkv = x @ qkv_w^T + qkv_b, scattered into Q/K/V (H,B,L,64)
    gemm_abT_bias<true><<<dim3(QKVN / BN, MROWS / BM), 256, 0, stream>>>(
        x, qkv_w, qkv_b, Q, QKVN, DDIM);

    // K2: fused scores + topk + softmax + sparse PV
    fused_attn<<<dim3(LSEQ / 4, BATCH, H), 256, 0, stream>>>(Q, Kb, V, S, attn);

    // K3: out = attn @ out_w^T + out_b
    gemm_abT_bias<false><<<dim3(DDIM / BN, MROWS / BM), 256, 0, stream>>>(
        attn, out_w, out_b, out, DDIM, DDIM);
}